// Round 6
// baseline (798.547 us; speedup 1.0000x reference)
//
#include <hip/hip_runtime.h>

#define NB 32768
#define DIN 256
#define NH 4096
#define NDOUT 256
#define DELTA 0.06f
#define CAND_CAP 4194304   // 16 MB / 4 B, aliases Xh region

typedef _Float16 f16x8 __attribute__((ext_vector_type(8)));
typedef _Float16 f16x4 __attribute__((ext_vector_type(4)));
typedef float f32x4 __attribute__((ext_vector_type(4)));

// ---------- numpy-pairwise-exact row sum-of-squares (n=256) ---------- (bit-exact, verified r3)
__global__ __launch_bounds__(256) void rowsumsq_kernel(const float* __restrict__ A,
                                                       float* __restrict__ out, int nrows) {
    int idx = blockIdx.x * 256 + threadIdx.x;
    int row = idx >> 3;
    int j   = idx & 7;
    if (row >= nrows) return;
    const float* a = A + (size_t)row * DIN;

    float v  = a[j];
    float rA = __fmul_rn(v, v);
#pragma unroll
    for (int t = 1; t < 16; ++t) { v = a[8 * t + j];       rA = __fadd_rn(rA, __fmul_rn(v, v)); }
    v = a[128 + j];
    float rB = __fmul_rn(v, v);
#pragma unroll
    for (int t = 1; t < 16; ++t) { v = a[128 + 8 * t + j]; rB = __fadd_rn(rB, __fmul_rn(v, v)); }

#pragma unroll
    for (int m = 1; m < 8; m <<= 1) {
        rA = __fadd_rn(rA, __shfl_xor(rA, m, 8));
        rB = __fadd_rn(rB, __shfl_xor(rB, m, 8));
    }
    if (j == 0) out[row] = __fadd_rn(rA, rB);
}

// ---------- Gt[h][d] = G[d][h] ----------
__global__ __launch_bounds__(256) void transpose_kernel(const float* __restrict__ G, float* __restrict__ Gt) {
    __shared__ float tile[32][33];
    int bh = blockIdx.x;
    int bd = blockIdx.y;
    int tx = threadIdx.x & 31, ty = threadIdx.x >> 5;
#pragma unroll
    for (int u = 0; u < 4; ++u) {
        int r = ty + u * 8;
        tile[r][tx] = G[(size_t)(bd * 32 + r) * NH + bh * 32 + tx];
    }
    __syncthreads();
#pragma unroll
    for (int u = 0; u < 4; ++u) {
        int r = ty + u * 8;
        Gt[(size_t)(bh * 32 + r) * NDOUT + bd * 32 + tx] = tile[tx][r];
    }
}

// ---------- fp32 -> fp16 convert (RN) ----------
__global__ __launch_bounds__(256) void tohalf_kernel(const float* __restrict__ in, _Float16* __restrict__ out, int n4) {
    int i = blockIdx.x * 256 + threadIdx.x;
    if (i >= n4) return;
    float4 v = reinterpret_cast<const float4*>(in)[i];
    f16x4 h;
    h[0] = (_Float16)v.x; h[1] = (_Float16)v.y; h[2] = (_Float16)v.z; h[3] = (_Float16)v.w;
    reinterpret_cast<f16x4*>(out)[i] = h;
}

// ---------- approx GEMM-argmin: fp16 MFMA, per-(row,16-col-tile) minima ---------- (unchanged r5)
__global__ __launch_bounds__(256) void approx_kernel(const _Float16* __restrict__ Xh, const _Float16* __restrict__ Wh,
                                                     const float* __restrict__ w2, float* __restrict__ tileMin) {
    __shared__ float4 A4[128 * 5];
    __shared__ float4 B4[128 * 5];
    const int tid  = threadIdx.x;
    const int lane = tid & 63;
    const int wid  = tid >> 6;
    const int wr = wid >> 1, wc = wid & 1;
    const int r0 = blockIdx.x * 128;
    const int c0 = blockIdx.y * 128;

    const float4* Xg = reinterpret_cast<const float4*>(Xh);
    const float4* Wg = reinterpret_cast<const float4*>(Wh);

    f32x4 acc[4][4];
#pragma unroll
    for (int i = 0; i < 4; ++i)
#pragma unroll
        for (int j = 0; j < 4; ++j) acc[i][j] = {0.f, 0.f, 0.f, 0.f};

    for (int kc8 = 0; kc8 < 32; kc8 += 4) {
        __syncthreads();
#pragma unroll
        for (int it = 0; it < 2; ++it) {
            int u = tid + 256 * it;
            int r = u >> 2, kg = u & 3;
            A4[r * 5 + kg] = Xg[(size_t)(r0 + r) * 32 + kc8 + kg];
            B4[r * 5 + kg] = Wg[(size_t)(c0 + r) * 32 + kc8 + kg];
        }
        __syncthreads();
        f16x8 af[4], bf[4];
#pragma unroll
        for (int fi = 0; fi < 4; ++fi)
            af[fi] = *reinterpret_cast<const f16x8*>(&A4[(wr * 64 + 16 * fi + (lane & 15)) * 5 + (lane >> 4)]);
#pragma unroll
        for (int fj = 0; fj < 4; ++fj)
            bf[fj] = *reinterpret_cast<const f16x8*>(&B4[(wc * 64 + 16 * fj + (lane & 15)) * 5 + (lane >> 4)]);
#pragma unroll
        for (int fi = 0; fi < 4; ++fi)
#pragma unroll
            for (int fj = 0; fj < 4; ++fj)
                acc[fi][fj] = __builtin_amdgcn_mfma_f32_16x16x32_f16(af[fi], bf[fj], acc[fi][fj], 0, 0, 0);
    }

#pragma unroll
    for (int fj = 0; fj < 4; ++fj) {
        int cb = c0 + wc * 64 + 16 * fj;
        float w2c = w2[cb + (lane & 15)];
        int ctile = cb >> 4;
#pragma unroll
        for (int fi = 0; fi < 4; ++fi) {
#pragma unroll
            for (int reg = 0; reg < 4; ++reg) {
                float d = fmaf(-2.f, acc[fi][fj][reg], w2c);
#pragma unroll
                for (int m = 1; m < 16; m <<= 1) d = fminf(d, __shfl_xor(d, m, 16));
                if ((lane & 15) == 0) {
                    int row = r0 + wr * 64 + 16 * fi + 4 * (lane >> 4) + reg;
                    tileMin[(size_t)row * 256 + ctile] = d;
                }
            }
        }
    }
}

// ---------- filter: per-row thr, append candidate (row,tile) pairs, init rowBest ----------
__global__ __launch_bounds__(256) void filter_kernel(const float* __restrict__ tileMin,
                                                     unsigned int* __restrict__ candList,
                                                     unsigned int* __restrict__ counter,
                                                     unsigned long long* __restrict__ rowBest) {
    const int lane = threadIdx.x & 63;
    const int wv   = threadIdx.x >> 6;
    const int row  = blockIdx.x * 4 + wv;

    float4 v4 = reinterpret_cast<const float4*>(tileMin)[(size_t)row * 64 + lane];
    float m0 = fminf(fminf(v4.x, v4.y), fminf(v4.z, v4.w));
#pragma unroll
    for (int i = 1; i < 64; i <<= 1) m0 = fminf(m0, __shfl_xor(m0, i, 64));
    const float thr = m0 + DELTA;

    float tv[4] = {v4.x, v4.y, v4.z, v4.w};
    int flag[4], pop = 0;
#pragma unroll
    for (int s = 0; s < 4; ++s) { flag[s] = (tv[s] <= thr); pop += flag[s]; }

    // wave inclusive scan of pop
    int incl = pop;
#pragma unroll
    for (int off = 1; off < 64; off <<= 1) {
        int n = __shfl_up(incl, off, 64);
        if (lane >= off) incl += n;
    }
    int total = __shfl(incl, 63, 64);
    unsigned int base = 0;
    if (lane == 63) base = atomicAdd(counter, (unsigned int)total);
    base = __shfl((int)base, 63, 64);
    int excl = incl - pop;

    int written = 0;
#pragma unroll
    for (int s = 0; s < 4; ++s) {
        if (flag[s]) {
            unsigned int pos = base + excl + written;
            if (pos < CAND_CAP) candList[pos] = (unsigned int)(row * 256 + lane * 4 + s);
            ++written;
        }
    }
    if (lane == 0) rowBest[row] = ~0ULL;
}

// ---------- rescore: one 16-lane group per candidate tile, exact d, atomicMin packed ----------
__device__ __forceinline__ unsigned long long packKey(float d, int c) {
    unsigned int u = __float_as_uint(d);
    u = (u & 0x80000000u) ? ~u : (u | 0x80000000u);   // monotone float->uint
    return ((unsigned long long)u << 32) | (unsigned int)c;
}

__global__ __launch_bounds__(256) void rescore2_kernel(const float* __restrict__ X, const float* __restrict__ W,
                                                       const float* __restrict__ x2, const float* __restrict__ w2,
                                                       const unsigned int* __restrict__ candList,
                                                       const unsigned int* __restrict__ counter,
                                                       unsigned long long* __restrict__ rowBest) {
    const int lane16 = threadIdx.x & 15;
    const int gid    = blockIdx.x * 16 + (threadIdx.x >> 4);
    const int nG     = gridDim.x * 16;
    const unsigned int total = *counter;
    const float4* X4 = reinterpret_cast<const float4*>(X);
    const float4* W4 = reinterpret_cast<const float4*>(W);

    for (unsigned int ci = gid; ci < total; ci += nG) {
        unsigned int e = candList[ci];
        int row  = e >> 8;
        int tile = e & 255;
        int c    = tile * 16 + lane16;

        const float4* Xr = X4 + (size_t)row * 64;
        const float4* Wr = W4 + (size_t)c * 64;
        // exact reference dot: sequential fmaf, k ascending
        float m = 0.f;
#pragma unroll 8
        for (int kk = 0; kk < 64; ++kk) {
            float4 wv = Wr[kk];
            float4 xv = Xr[kk];
            m = fmaf(xv.x, wv.x, m);
            m = fmaf(xv.y, wv.y, m);
            m = fmaf(xv.z, wv.z, m);
            m = fmaf(xv.w, wv.w, m);
        }
        float t = fmaf(-2.f, m, x2[row]);   // fl(x2 - 2m), 2m exact
        float d = __fadd_rn(t, w2[c]);      // fl(t + w2)

        float bv = d; int bi = c;
#pragma unroll
        for (int i = 1; i < 16; i <<= 1) {
            float ov = __shfl_xor(bv, i, 16);
            int   oi = __shfl_xor(bi, i, 16);
            if (ov < bv || (ov == bv && oi < bi)) { bv = ov; bi = oi; }
        }
        if (lane16 == 0) atomicMin(&rowBest[row], packKey(bv, bi));
    }
}

// ---------- gather: unpack winner, copy Gt row + index ----------
__global__ __launch_bounds__(256) void gather2_kernel(const float* __restrict__ Gt,
                                                      const unsigned long long* __restrict__ rowBest,
                                                      float* __restrict__ out) {
    const int lane = threadIdx.x & 63;
    const int wv   = threadIdx.x >> 6;
    const int r    = blockIdx.x * 4 + wv;
    int col = (int)(rowBest[r] & 0xFFFFFFFFULL);
    reinterpret_cast<float4*>(out)[(size_t)r * 64 + lane] =
        reinterpret_cast<const float4*>(Gt)[(size_t)col * 64 + lane];
    if (lane == 0) out[(size_t)NB * NDOUT + r] = (float)col;
}

extern "C" void kernel_launch(void* const* d_in, const int* in_sizes, int n_in,
                              void* d_out, int out_size, void* d_ws, size_t ws_size,
                              hipStream_t stream) {
    const float* x  = (const float*)d_in[0];
    const float* Wk = (const float*)d_in[1];
    const float* Gw = (const float*)d_in[2];
    float* out = (float*)d_out;

    char* ws = (char*)d_ws;
    float*     w2      = (float*)(ws);                         // 16 KB
    float*     x2      = (float*)(ws + (1u << 20));            // 128 KB
    float*     Gt      = (float*)(ws + (2u << 20));            // 4 MB
    _Float16*  Xh      = (_Float16*)(ws + (6u << 20));         // 16 MB (dead after approx)
    _Float16*  Wh      = (_Float16*)(ws + (22u << 20));        // 2 MB  (dead after approx)
    float*     tileMin = (float*)(ws + (24u << 20));           // 32 MB
    // aliases (used only after approx_kernel completes, stream-ordered):
    unsigned int*       candList = (unsigned int*)(ws + (6u << 20));        // over Xh, 16 MB
    unsigned int*       counter  = (unsigned int*)(ws + (22u << 20));       // over Wh
    unsigned long long* rowBest  = (unsigned long long*)(ws + (22u << 20) + 1024);  // 256 KB

    hipLaunchKernelGGL(rowsumsq_kernel,  dim3((NH * 8) / 256),       dim3(256), 0, stream, Wk, w2, NH);
    hipLaunchKernelGGL(rowsumsq_kernel,  dim3((NB * 8) / 256),       dim3(256), 0, stream, x, x2, NB);
    hipLaunchKernelGGL(transpose_kernel, dim3(NH / 32, NDOUT / 32),  dim3(256), 0, stream, Gw, Gt);
    hipLaunchKernelGGL(tohalf_kernel,    dim3((NB * DIN / 4) / 256), dim3(256), 0, stream, x, Xh, NB * DIN / 4);
    hipLaunchKernelGGL(tohalf_kernel,    dim3((NH * DIN / 4) / 256), dim3(256), 0, stream, Wk, Wh, NH * DIN / 4);
    hipLaunchKernelGGL(approx_kernel,    dim3(NB / 128, NH / 128),   dim3(256), 0, stream, Xh, Wh, w2, tileMin);
    hipMemsetAsync(counter, 0, sizeof(unsigned int), stream);
    hipLaunchKernelGGL(filter_kernel,    dim3(NB / 4),               dim3(256), 0, stream, tileMin, candList, counter, rowBest);
    hipLaunchKernelGGL(rescore2_kernel,  dim3(1024),                 dim3(256), 0, stream, x, Wk, x2, w2, candList, counter, rowBest);
    hipLaunchKernelGGL(gather2_kernel,   dim3(NB / 4),               dim3(256), 0, stream, Gt, rowBest, out);
}

// Round 7
// 684.495 us; speedup vs baseline: 1.1666x; 1.1666x over previous
//
#include <hip/hip_runtime.h>

#define NB 32768
#define DIN 256
#define NH 4096
#define NDOUT 256
#define DELTA 0.06f
#define ROWCAP 32

typedef _Float16 f16x8 __attribute__((ext_vector_type(8)));
typedef _Float16 f16x4 __attribute__((ext_vector_type(4)));
typedef float f32x4 __attribute__((ext_vector_type(4)));

// ---------- numpy-pairwise-exact row sum-of-squares (n=256) ---------- (bit-exact, verified r3)
__global__ __launch_bounds__(256) void rowsumsq_kernel(const float* __restrict__ A,
                                                       float* __restrict__ out, int nrows) {
    int idx = blockIdx.x * 256 + threadIdx.x;
    int row = idx >> 3;
    int j   = idx & 7;
    if (row >= nrows) return;
    const float* a = A + (size_t)row * DIN;

    float v  = a[j];
    float rA = __fmul_rn(v, v);
#pragma unroll
    for (int t = 1; t < 16; ++t) { v = a[8 * t + j];       rA = __fadd_rn(rA, __fmul_rn(v, v)); }
    v = a[128 + j];
    float rB = __fmul_rn(v, v);
#pragma unroll
    for (int t = 1; t < 16; ++t) { v = a[128 + 8 * t + j]; rB = __fadd_rn(rB, __fmul_rn(v, v)); }

#pragma unroll
    for (int m = 1; m < 8; m <<= 1) {
        rA = __fadd_rn(rA, __shfl_xor(rA, m, 8));
        rB = __fadd_rn(rB, __shfl_xor(rB, m, 8));
    }
    if (j == 0) out[row] = __fadd_rn(rA, rB);
}

// ---------- Gt[h][d] = G[d][h] ----------
__global__ __launch_bounds__(256) void transpose_kernel(const float* __restrict__ G, float* __restrict__ Gt) {
    __shared__ float tile[32][33];
    int bh = blockIdx.x;
    int bd = blockIdx.y;
    int tx = threadIdx.x & 31, ty = threadIdx.x >> 5;
#pragma unroll
    for (int u = 0; u < 4; ++u) {
        int r = ty + u * 8;
        tile[r][tx] = G[(size_t)(bd * 32 + r) * NH + bh * 32 + tx];
    }
    __syncthreads();
#pragma unroll
    for (int u = 0; u < 4; ++u) {
        int r = ty + u * 8;
        Gt[(size_t)(bh * 32 + r) * NDOUT + bd * 32 + tx] = tile[tx][r];
    }
}

// ---------- fp32 -> fp16 convert (RN) ----------
__global__ __launch_bounds__(256) void tohalf_kernel(const float* __restrict__ in, _Float16* __restrict__ out, int n4) {
    int i = blockIdx.x * 256 + threadIdx.x;
    if (i >= n4) return;
    float4 v = reinterpret_cast<const float4*>(in)[i];
    f16x4 h;
    h[0] = (_Float16)v.x; h[1] = (_Float16)v.y; h[2] = (_Float16)v.z; h[3] = (_Float16)v.w;
    reinterpret_cast<f16x4*>(out)[i] = h;
}

// ---------- approx GEMM-argmin: fp16 MFMA, per-(row,16-col-tile) minima ---------- (unchanged r5)
__global__ __launch_bounds__(256) void approx_kernel(const _Float16* __restrict__ Xh, const _Float16* __restrict__ Wh,
                                                     const float* __restrict__ w2, float* __restrict__ tileMin) {
    __shared__ float4 A4[128 * 5];
    __shared__ float4 B4[128 * 5];
    const int tid  = threadIdx.x;
    const int lane = tid & 63;
    const int wid  = tid >> 6;
    const int wr = wid >> 1, wc = wid & 1;
    const int r0 = blockIdx.x * 128;
    const int c0 = blockIdx.y * 128;

    const float4* Xg = reinterpret_cast<const float4*>(Xh);
    const float4* Wg = reinterpret_cast<const float4*>(Wh);

    f32x4 acc[4][4];
#pragma unroll
    for (int i = 0; i < 4; ++i)
#pragma unroll
        for (int j = 0; j < 4; ++j) acc[i][j] = {0.f, 0.f, 0.f, 0.f};

    for (int kc8 = 0; kc8 < 32; kc8 += 4) {
        __syncthreads();
#pragma unroll
        for (int it = 0; it < 2; ++it) {
            int u = tid + 256 * it;
            int r = u >> 2, kg = u & 3;
            A4[r * 5 + kg] = Xg[(size_t)(r0 + r) * 32 + kc8 + kg];
            B4[r * 5 + kg] = Wg[(size_t)(c0 + r) * 32 + kc8 + kg];
        }
        __syncthreads();
        f16x8 af[4], bf[4];
#pragma unroll
        for (int fi = 0; fi < 4; ++fi)
            af[fi] = *reinterpret_cast<const f16x8*>(&A4[(wr * 64 + 16 * fi + (lane & 15)) * 5 + (lane >> 4)]);
#pragma unroll
        for (int fj = 0; fj < 4; ++fj)
            bf[fj] = *reinterpret_cast<const f16x8*>(&B4[(wc * 64 + 16 * fj + (lane & 15)) * 5 + (lane >> 4)]);
#pragma unroll
        for (int fi = 0; fi < 4; ++fi)
#pragma unroll
            for (int fj = 0; fj < 4; ++fj)
                acc[fi][fj] = __builtin_amdgcn_mfma_f32_16x16x32_f16(af[fi], bf[fj], acc[fi][fj], 0, 0, 0);
    }

#pragma unroll
    for (int fj = 0; fj < 4; ++fj) {
        int cb = c0 + wc * 64 + 16 * fj;
        float w2c = w2[cb + (lane & 15)];
        int ctile = cb >> 4;
#pragma unroll
        for (int fi = 0; fi < 4; ++fi) {
#pragma unroll
            for (int reg = 0; reg < 4; ++reg) {
                float d = fmaf(-2.f, acc[fi][fj][reg], w2c);
#pragma unroll
                for (int m = 1; m < 16; m <<= 1) d = fminf(d, __shfl_xor(d, m, 16));
                if ((lane & 15) == 0) {
                    int row = r0 + wr * 64 + 16 * fi + 4 * (lane >> 4) + reg;
                    tileMin[(size_t)row * 256 + ctile] = d;
                }
            }
        }
    }
}

// ---------- filter: per-row threshold, per-row candidate slots, ZERO atomics ----------
__global__ __launch_bounds__(256) void filter_kernel(const float* __restrict__ tileMin,
                                                     unsigned char* __restrict__ candList,
                                                     int* __restrict__ candCount,
                                                     unsigned long long* __restrict__ rowBest) {
    const int lane = threadIdx.x & 63;
    const int wv   = threadIdx.x >> 6;
    const int row  = blockIdx.x * 4 + wv;

    float4 v4 = reinterpret_cast<const float4*>(tileMin)[(size_t)row * 64 + lane];
    float m0 = fminf(fminf(v4.x, v4.y), fminf(v4.z, v4.w));
#pragma unroll
    for (int i = 1; i < 64; i <<= 1) m0 = fminf(m0, __shfl_xor(m0, i, 64));
    const float thr = m0 + DELTA;

    float tv[4] = {v4.x, v4.y, v4.z, v4.w};
    int flag[4], pop = 0;
#pragma unroll
    for (int s = 0; s < 4; ++s) { flag[s] = (tv[s] <= thr); pop += flag[s]; }

    // wave-local inclusive scan of pop (scan logic validated r6)
    int incl = pop;
#pragma unroll
    for (int off = 1; off < 64; off <<= 1) {
        int n = __shfl_up(incl, off, 64);
        if (lane >= off) incl += n;
    }
    int excl = incl - pop;

    int written = 0;
#pragma unroll
    for (int s = 0; s < 4; ++s) {
        if (flag[s]) {
            int pos = excl + written;
            if (pos < ROWCAP) candList[(size_t)row * ROWCAP + pos] = (unsigned char)(lane * 4 + s);
            ++written;
        }
    }
    if (lane == 63) candCount[row] = incl;   // total candidates this row
    if (lane == 0)  rowBest[row] = ~0ULL;
}

// ---------- rescore: 16-lane group per (row,slot) pair, exact d, atomicMin packed ----------
__device__ __forceinline__ unsigned long long packKey(float d, int c) {
    unsigned int u = __float_as_uint(d);
    u = (u & 0x80000000u) ? ~u : (u | 0x80000000u);   // monotone float->uint
    return ((unsigned long long)u << 32) | (unsigned int)c;
}

__device__ __forceinline__ void rescore_tile(const float4* __restrict__ X4, const float4* __restrict__ W4,
                                             const float* __restrict__ x2, const float* __restrict__ w2,
                                             int row, int tile, int lane16,
                                             unsigned long long* __restrict__ rowBest) {
    int c = tile * 16 + lane16;
    const float4* Xr = X4 + (size_t)row * 64;
    const float4* Wr = W4 + (size_t)c * 64;
    // exact reference dot: sequential fmaf, k ascending
    float m = 0.f;
#pragma unroll 8
    for (int kk = 0; kk < 64; ++kk) {
        float4 wv = Wr[kk];
        float4 xv = Xr[kk];
        m = fmaf(xv.x, wv.x, m);
        m = fmaf(xv.y, wv.y, m);
        m = fmaf(xv.z, wv.z, m);
        m = fmaf(xv.w, wv.w, m);
    }
    float t = fmaf(-2.f, m, x2[row]);   // fl(x2 - 2m), 2m exact
    float d = __fadd_rn(t, w2[c]);      // fl(t + w2)

    float bv = d; int bi = c;
#pragma unroll
    for (int i = 1; i < 16; i <<= 1) {
        float ov = __shfl_xor(bv, i, 16);
        int   oi = __shfl_xor(bi, i, 16);
        if (ov < bv || (ov == bv && oi < bi)) { bv = ov; bi = oi; }
    }
    if (lane16 == 0) atomicMin(&rowBest[row], packKey(bv, bi));
}

__global__ __launch_bounds__(256) void rescore2_kernel(const float* __restrict__ X, const float* __restrict__ W,
                                                       const float* __restrict__ x2, const float* __restrict__ w2,
                                                       const unsigned char* __restrict__ candList,
                                                       const int* __restrict__ candCount,
                                                       unsigned long long* __restrict__ rowBest) {
    const int lane16 = threadIdx.x & 15;
    const int gid    = blockIdx.x * 16 + (threadIdx.x >> 4);
    const int nG     = gridDim.x * 16;
    const float4* X4 = reinterpret_cast<const float4*>(X);
    const float4* W4 = reinterpret_cast<const float4*>(W);
    const int totalPairs = NB * ROWCAP;

    for (int p = gid; p < totalPairs; p += nG) {
        int row = p >> 5, slot = p & (ROWCAP - 1);
        int cnt = candCount[row];
        if (cnt <= ROWCAP) {
            if (slot >= cnt) continue;
            int tile = candList[(size_t)row * ROWCAP + slot];
            rescore_tile(X4, W4, x2, w2, row, tile, lane16, rowBest);
        } else {
            // overflow (cnt > ROWCAP): stored slots are incomplete -> cover ALL tiles, strided
            for (int tile = slot; tile < 256; tile += ROWCAP)
                rescore_tile(X4, W4, x2, w2, row, tile, lane16, rowBest);
        }
    }
}

// ---------- gather: unpack winner, copy Gt row + index ----------
__global__ __launch_bounds__(256) void gather2_kernel(const float* __restrict__ Gt,
                                                      const unsigned long long* __restrict__ rowBest,
                                                      float* __restrict__ out) {
    const int lane = threadIdx.x & 63;
    const int wv   = threadIdx.x >> 6;
    const int r    = blockIdx.x * 4 + wv;
    int col = (int)(rowBest[r] & 0xFFFFFFFFULL);
    reinterpret_cast<float4*>(out)[(size_t)r * 64 + lane] =
        reinterpret_cast<const float4*>(Gt)[(size_t)col * 64 + lane];
    if (lane == 0) out[(size_t)NB * NDOUT + r] = (float)col;
}

extern "C" void kernel_launch(void* const* d_in, const int* in_sizes, int n_in,
                              void* d_out, int out_size, void* d_ws, size_t ws_size,
                              hipStream_t stream) {
    const float* x  = (const float*)d_in[0];
    const float* Wk = (const float*)d_in[1];
    const float* Gw = (const float*)d_in[2];
    float* out = (float*)d_out;

    char* ws = (char*)d_ws;
    float*     w2      = (float*)(ws);                         // 16 KB
    float*     x2      = (float*)(ws + (1u << 20));            // 128 KB
    float*     Gt      = (float*)(ws + (2u << 20));            // 4 MB
    _Float16*  Xh      = (_Float16*)(ws + (6u << 20));         // 16 MB (dead after approx)
    _Float16*  Wh      = (_Float16*)(ws + (22u << 20));        // 2 MB
    float*     tileMin = (float*)(ws + (24u << 20));           // 32 MB
    // aliases over Xh region (used only after approx_kernel completes, stream-ordered):
    unsigned char*      candList  = (unsigned char*)(ws + (6u << 20));            // 1 MB
    int*                candCount = (int*)(ws + (7u << 20));                      // 128 KB
    unsigned long long* rowBest   = (unsigned long long*)(ws + (8u << 20));       // 256 KB

    hipLaunchKernelGGL(rowsumsq_kernel,  dim3((NH * 8) / 256),       dim3(256), 0, stream, Wk, w2, NH);
    hipLaunchKernelGGL(rowsumsq_kernel,  dim3((NB * 8) / 256),       dim3(256), 0, stream, x, x2, NB);
    hipLaunchKernelGGL(transpose_kernel, dim3(NH / 32, NDOUT / 32),  dim3(256), 0, stream, Gw, Gt);
    hipLaunchKernelGGL(tohalf_kernel,    dim3((NB * DIN / 4) / 256), dim3(256), 0, stream, x, Xh, NB * DIN / 4);
    hipLaunchKernelGGL(tohalf_kernel,    dim3((NH * DIN / 4) / 256), dim3(256), 0, stream, Wk, Wh, NH * DIN / 4);
    hipLaunchKernelGGL(approx_kernel,    dim3(NB / 128, NH / 128),   dim3(256), 0, stream, Xh, Wh, w2, tileMin);
    hipLaunchKernelGGL(filter_kernel,    dim3(NB / 4),               dim3(256), 0, stream, tileMin, candList, candCount, rowBest);
    hipLaunchKernelGGL(rescore2_kernel,  dim3(2048),                 dim3(256), 0, stream, x, Wk, x2, w2, candList, candCount, rowBest);
    hipLaunchKernelGGL(gather2_kernel,   dim3(NB / 4),               dim3(256), 0, stream, Gt, rowBest, out);
}

// Round 8
// 427.921 us; speedup vs baseline: 1.8661x; 1.5996x over previous
//
#include <hip/hip_runtime.h>

#define NB 32768
#define DIN 256
#define NH 4096
#define NDOUT 256
#define DELTA 0.06f
#define ROWCAP 32

typedef _Float16 f16x8 __attribute__((ext_vector_type(8)));
typedef _Float16 f16x4 __attribute__((ext_vector_type(4)));
typedef float f32x4 __attribute__((ext_vector_type(4)));

// ---------- numpy-pairwise-exact row sum-of-squares (n=256) ---------- (bit-exact, verified r3)
__global__ __launch_bounds__(256) void rowsumsq_kernel(const float* __restrict__ A,
                                                       float* __restrict__ out, int nrows) {
    int idx = blockIdx.x * 256 + threadIdx.x;
    int row = idx >> 3;
    int j   = idx & 7;
    if (row >= nrows) return;
    const float* a = A + (size_t)row * DIN;

    float v  = a[j];
    float rA = __fmul_rn(v, v);
#pragma unroll
    for (int t = 1; t < 16; ++t) { v = a[8 * t + j];       rA = __fadd_rn(rA, __fmul_rn(v, v)); }
    v = a[128 + j];
    float rB = __fmul_rn(v, v);
#pragma unroll
    for (int t = 1; t < 16; ++t) { v = a[128 + 8 * t + j]; rB = __fadd_rn(rB, __fmul_rn(v, v)); }

#pragma unroll
    for (int m = 1; m < 8; m <<= 1) {
        rA = __fadd_rn(rA, __shfl_xor(rA, m, 8));
        rB = __fadd_rn(rB, __shfl_xor(rB, m, 8));
    }
    if (j == 0) out[row] = __fadd_rn(rA, rB);
}

// ---------- Gt[h][d] = G[d][h] ----------
__global__ __launch_bounds__(256) void transpose_kernel(const float* __restrict__ G, float* __restrict__ Gt) {
    __shared__ float tile[32][33];
    int bh = blockIdx.x;
    int bd = blockIdx.y;
    int tx = threadIdx.x & 31, ty = threadIdx.x >> 5;
#pragma unroll
    for (int u = 0; u < 4; ++u) {
        int r = ty + u * 8;
        tile[r][tx] = G[(size_t)(bd * 32 + r) * NH + bh * 32 + tx];
    }
    __syncthreads();
#pragma unroll
    for (int u = 0; u < 4; ++u) {
        int r = ty + u * 8;
        Gt[(size_t)(bh * 32 + r) * NDOUT + bd * 32 + tx] = tile[tx][r];
    }
}

// ---------- fp32 -> fp16 convert (RN) ----------
__global__ __launch_bounds__(256) void tohalf_kernel(const float* __restrict__ in, _Float16* __restrict__ out, int n4) {
    int i = blockIdx.x * 256 + threadIdx.x;
    if (i >= n4) return;
    float4 v = reinterpret_cast<const float4*>(in)[i];
    f16x4 h;
    h[0] = (_Float16)v.x; h[1] = (_Float16)v.y; h[2] = (_Float16)v.z; h[3] = (_Float16)v.w;
    reinterpret_cast<f16x4*>(out)[i] = h;
}

// ---------- approx GEMM-argmin: fp16 MFMA, per-(row,16-col-tile) minima ---------- (unchanged r5)
__global__ __launch_bounds__(256) void approx_kernel(const _Float16* __restrict__ Xh, const _Float16* __restrict__ Wh,
                                                     const float* __restrict__ w2, float* __restrict__ tileMin) {
    __shared__ float4 A4[128 * 5];
    __shared__ float4 B4[128 * 5];
    const int tid  = threadIdx.x;
    const int lane = tid & 63;
    const int wid  = tid >> 6;
    const int wr = wid >> 1, wc = wid & 1;
    const int r0 = blockIdx.x * 128;
    const int c0 = blockIdx.y * 128;

    const float4* Xg = reinterpret_cast<const float4*>(Xh);
    const float4* Wg = reinterpret_cast<const float4*>(Wh);

    f32x4 acc[4][4];
#pragma unroll
    for (int i = 0; i < 4; ++i)
#pragma unroll
        for (int j = 0; j < 4; ++j) acc[i][j] = {0.f, 0.f, 0.f, 0.f};

    for (int kc8 = 0; kc8 < 32; kc8 += 4) {
        __syncthreads();
#pragma unroll
        for (int it = 0; it < 2; ++it) {
            int u = tid + 256 * it;
            int r = u >> 2, kg = u & 3;
            A4[r * 5 + kg] = Xg[(size_t)(r0 + r) * 32 + kc8 + kg];
            B4[r * 5 + kg] = Wg[(size_t)(c0 + r) * 32 + kc8 + kg];
        }
        __syncthreads();
        f16x8 af[4], bf[4];
#pragma unroll
        for (int fi = 0; fi < 4; ++fi)
            af[fi] = *reinterpret_cast<const f16x8*>(&A4[(wr * 64 + 16 * fi + (lane & 15)) * 5 + (lane >> 4)]);
#pragma unroll
        for (int fj = 0; fj < 4; ++fj)
            bf[fj] = *reinterpret_cast<const f16x8*>(&B4[(wc * 64 + 16 * fj + (lane & 15)) * 5 + (lane >> 4)]);
#pragma unroll
        for (int fi = 0; fi < 4; ++fi)
#pragma unroll
            for (int fj = 0; fj < 4; ++fj)
                acc[fi][fj] = __builtin_amdgcn_mfma_f32_16x16x32_f16(af[fi], bf[fj], acc[fi][fj], 0, 0, 0);
    }

#pragma unroll
    for (int fj = 0; fj < 4; ++fj) {
        int cb = c0 + wc * 64 + 16 * fj;
        float w2c = w2[cb + (lane & 15)];
        int ctile = cb >> 4;
#pragma unroll
        for (int fi = 0; fi < 4; ++fi) {
#pragma unroll
            for (int reg = 0; reg < 4; ++reg) {
                float d = fmaf(-2.f, acc[fi][fj][reg], w2c);
#pragma unroll
                for (int m = 1; m < 16; m <<= 1) d = fminf(d, __shfl_xor(d, m, 16));
                if ((lane & 15) == 0) {
                    int row = r0 + wr * 64 + 16 * fi + 4 * (lane >> 4) + reg;
                    tileMin[(size_t)row * 256 + ctile] = d;
                }
            }
        }
    }
}

// ---------- filter: per-row threshold, per-row candidate slots, zero atomics (verified r7) ----------
__global__ __launch_bounds__(256) void filter_kernel(const float* __restrict__ tileMin,
                                                     unsigned char* __restrict__ candList,
                                                     int* __restrict__ candCount,
                                                     unsigned long long* __restrict__ rowBest) {
    const int lane = threadIdx.x & 63;
    const int wv   = threadIdx.x >> 6;
    const int row  = blockIdx.x * 4 + wv;

    float4 v4 = reinterpret_cast<const float4*>(tileMin)[(size_t)row * 64 + lane];
    float m0 = fminf(fminf(v4.x, v4.y), fminf(v4.z, v4.w));
#pragma unroll
    for (int i = 1; i < 64; i <<= 1) m0 = fminf(m0, __shfl_xor(m0, i, 64));
    const float thr = m0 + DELTA;

    float tv[4] = {v4.x, v4.y, v4.z, v4.w};
    int flag[4], pop = 0;
#pragma unroll
    for (int s = 0; s < 4; ++s) { flag[s] = (tv[s] <= thr); pop += flag[s]; }

    int incl = pop;
#pragma unroll
    for (int off = 1; off < 64; off <<= 1) {
        int n = __shfl_up(incl, off, 64);
        if (lane >= off) incl += n;
    }
    int excl = incl - pop;

    int written = 0;
#pragma unroll
    for (int s = 0; s < 4; ++s) {
        if (flag[s]) {
            int pos = excl + written;
            if (pos < ROWCAP) candList[(size_t)row * ROWCAP + pos] = (unsigned char)(lane * 4 + s);
            ++written;
        }
    }
    if (lane == 63) candCount[row] = incl;
    if (lane == 0)  rowBest[row] = ~0ULL;
}

// ---------- scan: ONE block; exclusive scan of min(cnt,ROWCAP) over NB rows ----------
__global__ __launch_bounds__(256) void scan_kernel(const int* __restrict__ candCount,
                                                   int* __restrict__ rowBase,
                                                   int* __restrict__ totalCand) {
    __shared__ int wsum[4];
    const int t = threadIdx.x;
    const int lane = t & 63, wv = t >> 6;
    const int base = t * (NB / 256);   // 128 rows per thread

    int s = 0;
    for (int i = 0; i < NB / 256; ++i) {
        int c = candCount[base + i];
        s += (c > ROWCAP ? ROWCAP : c);
    }
    int incl = s;
#pragma unroll
    for (int off = 1; off < 64; off <<= 1) {
        int n = __shfl_up(incl, off, 64);
        if (lane >= off) incl += n;
    }
    if (lane == 63) wsum[wv] = incl;
    __syncthreads();
    int wadd = 0;
    for (int w = 0; w < wv; ++w) wadd += wsum[w];
    int run = wadd + incl - s;     // exclusive prefix of this thread's chunk
    for (int i = 0; i < NB / 256; ++i) {
        int c = candCount[base + i];
        int e = (c > ROWCAP ? ROWCAP : c);
        rowBase[base + i] = run;
        run += e;
    }
    if (t == 255) totalCand[0] = run;
}

// ---------- scatter: wave/row, write dense entries ----------
// entry: bit31 = overflow flag; bits [22:8] = row; bits [7:0] = tile (or stride-slot if overflow)
__global__ __launch_bounds__(256) void scatter_kernel(const unsigned char* __restrict__ candList,
                                                      const int* __restrict__ candCount,
                                                      const int* __restrict__ rowBase,
                                                      unsigned int* __restrict__ dense) {
    const int lane = threadIdx.x & 63;
    const int wv   = threadIdx.x >> 6;
    const int row  = blockIdx.x * 4 + wv;
    const int cnt  = candCount[row];
    const int base = rowBase[row];
    if (cnt <= ROWCAP) {
        if (lane < cnt)
            dense[base + lane] = ((unsigned int)row << 8) | candList[(size_t)row * ROWCAP + lane];
    } else {
        if (lane < ROWCAP)
            dense[base + lane] = 0x80000000u | ((unsigned int)row << 8) | (unsigned int)lane;
    }
}

// ---------- rescore: 16-lane group per dense entry, exact d, atomicMin packed ----------
__device__ __forceinline__ unsigned long long packKey(float d, int c) {
    unsigned int u = __float_as_uint(d);
    u = (u & 0x80000000u) ? ~u : (u | 0x80000000u);   // monotone float->uint
    return ((unsigned long long)u << 32) | (unsigned int)c;
}

__device__ __forceinline__ void rescore_tile(const float4* __restrict__ X4, const float4* __restrict__ W4,
                                             const float* __restrict__ x2, const float* __restrict__ w2,
                                             int row, int tile, int lane16,
                                             unsigned long long* __restrict__ rowBest) {
    int c = tile * 16 + lane16;
    const float4* Xr = X4 + (size_t)row * 64;
    const float4* Wr = W4 + (size_t)c * 64;
    // exact reference dot: sequential fmaf, k ascending
    float m = 0.f;
#pragma unroll 8
    for (int kk = 0; kk < 64; ++kk) {
        float4 wv = Wr[kk];
        float4 xv = Xr[kk];
        m = fmaf(xv.x, wv.x, m);
        m = fmaf(xv.y, wv.y, m);
        m = fmaf(xv.z, wv.z, m);
        m = fmaf(xv.w, wv.w, m);
    }
    float t = fmaf(-2.f, m, x2[row]);   // fl(x2 - 2m), 2m exact
    float d = __fadd_rn(t, w2[c]);      // fl(t + w2)

    float bv = d; int bi = c;
#pragma unroll
    for (int i = 1; i < 16; i <<= 1) {
        float ov = __shfl_xor(bv, i, 16);
        int   oi = __shfl_xor(bi, i, 16);
        if (ov < bv || (ov == bv && oi < bi)) { bv = ov; bi = oi; }
    }
    if (lane16 == 0) atomicMin(&rowBest[row], packKey(bv, bi));
}

__global__ __launch_bounds__(256) void rescore_dense(const float* __restrict__ X, const float* __restrict__ W,
                                                     const float* __restrict__ x2, const float* __restrict__ w2,
                                                     const unsigned int* __restrict__ dense,
                                                     const int* __restrict__ totalCand,
                                                     unsigned long long* __restrict__ rowBest) {
    const int lane16 = threadIdx.x & 15;
    const int gid    = blockIdx.x * 16 + (threadIdx.x >> 4);
    const int nG     = gridDim.x * 16;
    const int total  = *totalCand;
    const float4* X4 = reinterpret_cast<const float4*>(X);
    const float4* W4 = reinterpret_cast<const float4*>(W);

    for (int ci = gid; ci < total; ci += nG) {
        unsigned int e = dense[ci];
        int row = (int)((e >> 8) & 0x7FFF);
        if (e & 0x80000000u) {
            int slot = (int)(e & 255u);
            for (int tile = slot; tile < 256; tile += ROWCAP)
                rescore_tile(X4, W4, x2, w2, row, tile, lane16, rowBest);
        } else {
            int tile = (int)(e & 255u);
            rescore_tile(X4, W4, x2, w2, row, tile, lane16, rowBest);
        }
    }
}

// ---------- gather: unpack winner, copy Gt row + index ----------
__global__ __launch_bounds__(256) void gather2_kernel(const float* __restrict__ Gt,
                                                      const unsigned long long* __restrict__ rowBest,
                                                      float* __restrict__ out) {
    const int lane = threadIdx.x & 63;
    const int wv   = threadIdx.x >> 6;
    const int r    = blockIdx.x * 4 + wv;
    int col = (int)(rowBest[r] & 0xFFFFFFFFULL);
    reinterpret_cast<float4*>(out)[(size_t)r * 64 + lane] =
        reinterpret_cast<const float4*>(Gt)[(size_t)col * 64 + lane];
    if (lane == 0) out[(size_t)NB * NDOUT + r] = (float)col;
}

extern "C" void kernel_launch(void* const* d_in, const int* in_sizes, int n_in,
                              void* d_out, int out_size, void* d_ws, size_t ws_size,
                              hipStream_t stream) {
    const float* x  = (const float*)d_in[0];
    const float* Wk = (const float*)d_in[1];
    const float* Gw = (const float*)d_in[2];
    float* out = (float*)d_out;

    char* ws = (char*)d_ws;
    float*     w2      = (float*)(ws);                         // 16 KB
    float*     x2      = (float*)(ws + (1u << 20));            // 128 KB
    float*     Gt      = (float*)(ws + (2u << 20));            // 4 MB
    _Float16*  Xh      = (_Float16*)(ws + (6u << 20));         // 16 MB (dead after approx)
    _Float16*  Wh      = (_Float16*)(ws + (22u << 20));        // 2 MB
    float*     tileMin = (float*)(ws + (24u << 20));           // 32 MB
    // aliases over Xh region (used only after approx_kernel completes, stream-ordered):
    unsigned char*      candList  = (unsigned char*)(ws + (6u << 20));              // 1 MB
    int*                candCount = (int*)(ws + (7u << 20));                        // 128 KB
    int*                totalCand = (int*)(ws + (7u << 20) + (256u << 10));         // 4 B
    int*                rowBase   = (int*)(ws + (7u << 20) + (512u << 10));         // 128 KB
    unsigned long long* rowBest   = (unsigned long long*)(ws + (8u << 20));         // 256 KB
    unsigned int*       dense     = (unsigned int*)(ws + (9u << 20));               // 4 MB

    hipLaunchKernelGGL(rowsumsq_kernel,  dim3((NH * 8) / 256),       dim3(256), 0, stream, Wk, w2, NH);
    hipLaunchKernelGGL(rowsumsq_kernel,  dim3((NB * 8) / 256),       dim3(256), 0, stream, x, x2, NB);
    hipLaunchKernelGGL(transpose_kernel, dim3(NH / 32, NDOUT / 32),  dim3(256), 0, stream, Gw, Gt);
    hipLaunchKernelGGL(tohalf_kernel,    dim3((NB * DIN / 4) / 256), dim3(256), 0, stream, x, Xh, NB * DIN / 4);
    hipLaunchKernelGGL(tohalf_kernel,    dim3((NH * DIN / 4) / 256), dim3(256), 0, stream, Wk, Wh, NH * DIN / 4);
    hipLaunchKernelGGL(approx_kernel,    dim3(NB / 128, NH / 128),   dim3(256), 0, stream, Xh, Wh, w2, tileMin);
    hipLaunchKernelGGL(filter_kernel,    dim3(NB / 4),               dim3(256), 0, stream, tileMin, candList, candCount, rowBest);
    hipLaunchKernelGGL(scan_kernel,      dim3(1),                    dim3(256), 0, stream, candCount, rowBase, totalCand);
    hipLaunchKernelGGL(scatter_kernel,   dim3(NB / 4),               dim3(256), 0, stream, candList, candCount, rowBase, dense);
    hipLaunchKernelGGL(rescore_dense,    dim3(1024),                 dim3(256), 0, stream, x, Wk, x2, w2, dense, totalCand, rowBest);
    hipLaunchKernelGGL(gather2_kernel,   dim3(NB / 4),               dim3(256), 0, stream, Gt, rowBest, out);
}